// Round 1
// baseline (300.216 us; speedup 1.0000x reference)
//
#include <hip/hip_runtime.h>
#include <hip/hip_bf16.h>

typedef __attribute__((ext_vector_type(8))) short short8;
typedef __attribute__((ext_vector_type(4))) float f32x4;
typedef __attribute__((ext_vector_type(4))) float float4v;
typedef __attribute__((ext_vector_type(8))) unsigned short ushort8;
typedef __attribute__((ext_vector_type(4))) unsigned short ushort4v;

__device__ __forceinline__ unsigned short f2bf(float f) {
  union { float f; unsigned u; } a; a.f = f;
  unsigned u = a.u;
  u += 0x7FFFu + ((u >> 16) & 1u);   // RTNE
  return (unsigned short)(u >> 16);
}

__device__ __forceinline__ void gload_lds16(const void* g, void* l) {
  __builtin_amdgcn_global_load_lds(
      (const __attribute__((address_space(1))) unsigned int*)g,
      (__attribute__((address_space(3))) unsigned int*)l, 16, 0, 0);
}

// ---------------- f32 -> bf16 convert (vectorized, grid-stride) ----------------
__global__ void cvt_bf16(const float* __restrict__ in, unsigned short* __restrict__ out, long n) {
  long i = ((long)blockIdx.x * blockDim.x + threadIdx.x) * 4;
  long stride = (long)gridDim.x * blockDim.x * 4;
  for (; i < n; i += stride) {
    float4v x = *(const float4v*)(in + i);
    ushort4v o;
    o.x = f2bf(x.x); o.y = f2bf(x.y); o.z = f2bf(x.z); o.w = f2bf(x.w);
    *(ushort4v*)(out + i) = o;
  }
}

// ------------- transpose + convert: W[R][C] f32 -> WT[C][R] bf16 ---------------
__global__ void cvt_transpose(const float* __restrict__ in, unsigned short* __restrict__ out,
                              int R, int C) {
  __shared__ float tile[32][33];
  int c0 = blockIdx.x * 32, r0 = blockIdx.y * 32;
#pragma unroll
  for (int i = 0; i < 4; ++i) {
    int r = r0 + threadIdx.y + i * 8;
    tile[threadIdx.y + i * 8][threadIdx.x] = in[(long)r * C + c0 + threadIdx.x];
  }
  __syncthreads();
#pragma unroll
  for (int i = 0; i < 4; ++i) {
    int rr = threadIdx.y + i * 8;           // out row within tile (= in col)
    int cc = threadIdx.x;                   // out col within tile (= in row)
    out[(long)(c0 + rr) * R + r0 + cc] = f2bf(tile[cc][rr]);
  }
}

// ---------------- NT GEMM: C[M,N] = A[M,K] * Bt[N,K]^T  (bf16 in) ----------------
// 128x128 tile, BK=32, 256 threads (4 waves, each 64x64), mfma_f32_16x16x32_bf16.
// LDS slots are XOR-swizzled: slot(r,u) = (4r+u) ^ (r&7); staging pre-swizzles the
// global source so global_load_lds stays linear; reads apply the same mapping.
template<int OUT_BF16, int BIAS_MODE>  // BIAS_MODE: 0 none, 1 per-col, 2 per-row
__global__ __launch_bounds__(256)
void gemm_nt(const unsigned short* __restrict__ A, int lda, long strideA,
             const unsigned short* __restrict__ Bt, int ldb, long strideB,
             void* __restrict__ Cv, int ldc, long strideC,
             const float* __restrict__ bias, float scale, int K) {
  __shared__ char lds[16384];
  const int tid = threadIdx.x;
  const int m0 = blockIdx.y * 128;
  const int n0 = blockIdx.x * 128;
  const int batch = blockIdx.z;
  A += batch * strideA;
  Bt += batch * strideB;

  const int wave = tid >> 6, lane = tid & 63;
  const int wr = (wave >> 1) * 64, wc = (wave & 1) * 64;
  const int lr = lane & 15, lk = lane >> 4;

  // fragment LDS byte offsets (loop-invariant)
  int aoff[4], boff[4];
#pragma unroll
  for (int m = 0; m < 4; ++m) {
    int ra = wr + m * 16 + lr;
    aoff[m] = ((ra * 4 + lk) ^ (ra & 7)) << 4;
    int rb = wc + m * 16 + lr;
    boff[m] = 8192 + ((((rb * 4 + lk) ^ (rb & 7))) << 4);
  }

  // staging: slot s -> (row r, k-unit u) inverse of slot(r,u) = (4r+u)^(r&7)
  int strow[2], stu[2];
#pragma unroll
  for (int p = 0; p < 2; ++p) {
    int s = p * 256 + tid;
    int r = ((s >> 3) << 1) | (((s >> 2) & 1) ^ ((s >> 4) & 1));
    int u = (s & 3) ^ (r & 3);
    strow[p] = r; stu[p] = u;
  }

  f32x4 acc[4][4];
#pragma unroll
  for (int m = 0; m < 4; ++m)
#pragma unroll
    for (int n = 0; n < 4; ++n) acc[m][n] = f32x4{0.f, 0.f, 0.f, 0.f};

  for (int k0 = 0; k0 < K; k0 += 32) {
#pragma unroll
    for (int p = 0; p < 2; ++p) {
      int s = p * 256 + tid;
      gload_lds16(A + (long)(m0 + strow[p]) * lda + k0 + stu[p] * 8, lds + s * 16);
      gload_lds16(Bt + (long)(n0 + strow[p]) * ldb + k0 + stu[p] * 8, lds + 8192 + s * 16);
    }
    __syncthreads();   // drains vmcnt before barrier (compiler-enforced)
    short8 af[4], bf[4];
#pragma unroll
    for (int m = 0; m < 4; ++m) af[m] = *(const short8*)(lds + aoff[m]);
#pragma unroll
    for (int n = 0; n < 4; ++n) bf[n] = *(const short8*)(lds + boff[n]);
#pragma unroll
    for (int m = 0; m < 4; ++m)
#pragma unroll
      for (int n = 0; n < 4; ++n)
        acc[m][n] = __builtin_amdgcn_mfma_f32_16x16x32_bf16(af[m], bf[n], acc[m][n], 0, 0, 0);
    __syncthreads();
  }

  // epilogue: C/D layout col = lane&15, row = (lane>>4)*4 + reg
#pragma unroll
  for (int m = 0; m < 4; ++m) {
#pragma unroll
    for (int n = 0; n < 4; ++n) {
      int col = n0 + wc + n * 16 + lr;
      float bc = (BIAS_MODE == 1) ? bias[col] : 0.f;
#pragma unroll
      for (int j = 0; j < 4; ++j) {
        int row = m0 + wr + m * 16 + lk * 4 + j;
        float val = acc[m][n][j] * scale + bc;
        if (BIAS_MODE == 2) val += bias[row];
        if (OUT_BF16)
          ((unsigned short*)Cv)[batch * strideC + (long)row * ldc + col] = f2bf(val);
        else
          ((float*)Cv)[batch * strideC + (long)row * ldc + col] = val;
      }
    }
  }
}

// --------- row softmax: scores f32 [8192][2048] -> P bf16 in-place (lda 4096) ---------
__global__ __launch_bounds__(256)
void softmax_rows(float* __restrict__ sc) {
  long row = blockIdx.x;
  float* p = sc + row * 2048;
  int tid = threadIdx.x;
  int wave = tid >> 6;

  float v[8];
  float4v x0 = *(const float4v*)(p + tid * 8);
  float4v x1 = *(const float4v*)(p + tid * 8 + 4);
  v[0] = x0.x; v[1] = x0.y; v[2] = x0.z; v[3] = x0.w;
  v[4] = x1.x; v[5] = x1.y; v[6] = x1.z; v[7] = x1.w;

  float m = -1e30f;
#pragma unroll
  for (int j = 0; j < 8; ++j) m = fmaxf(m, v[j]);
#pragma unroll
  for (int o = 32; o; o >>= 1) m = fmaxf(m, __shfl_xor(m, o));
  __shared__ float redm[4], reds[4];
  if ((tid & 63) == 0) redm[wave] = m;
  __syncthreads();
  m = fmaxf(fmaxf(redm[0], redm[1]), fmaxf(redm[2], redm[3]));

  float s = 0.f;
#pragma unroll
  for (int j = 0; j < 8; ++j) { v[j] = __expf(v[j] - m); s += v[j]; }
#pragma unroll
  for (int o = 32; o; o >>= 1) s += __shfl_xor(s, o);
  if ((tid & 63) == 0) reds[wave] = s;
  __syncthreads();
  s = reds[0] + reds[1] + reds[2] + reds[3];
  float inv = 1.0f / s;

  ushort8 o8;
#pragma unroll
  for (int j = 0; j < 8; ++j) o8[j] = f2bf(v[j] * inv);
  *(ushort8*)((unsigned short*)p + tid * 8) = o8;   // safe: all reads completed pre-barrier
}

// ------------------------------------------------------------------------------
extern "C" void kernel_launch(void* const* d_in, const int* in_sizes, int n_in,
                              void* d_out, int out_size, void* d_ws, size_t ws_size,
                              hipStream_t stream) {
  const float* X  = (const float*)d_in[0];
  const float* Wq = (const float*)d_in[1];
  const float* bq = (const float*)d_in[2];
  const float* Wk = (const float*)d_in[3];
  const float* bk = (const float*)d_in[4];
  const float* Wv = (const float*)d_in[5];
  const float* bv = (const float*)d_in[6];
  float* out = (float*)d_out;

  char* ws = (char*)d_ws;
  unsigned short* Xb  = (unsigned short*)(ws);                       // 16 MiB [8192,1024]
  unsigned short* WqT = (unsigned short*)(ws + (16l << 20));         //  1 MiB [512,1024]
  unsigned short* WkT = (unsigned short*)(ws + (17l << 20));         //  1 MiB
  unsigned short* WvT = (unsigned short*)(ws + (18l << 20));         //  2 MiB [1024,1024]
  unsigned short* Qb  = (unsigned short*)(ws + (20l << 20));         //  8 MiB [8192,512]
  unsigned short* Kb  = (unsigned short*)(ws + (28l << 20));         //  8 MiB
  unsigned short* VT  = (unsigned short*)(ws + (36l << 20));         // 16 MiB [1024,8192]
  float*          SC  = (float*)         (ws + (52l << 20));         // 64 MiB [4][2048][2048]

  // 1) conversions
  cvt_bf16<<<4096, 256, 0, stream>>>(X, Xb, 8388608);
  cvt_transpose<<<dim3(16, 32), dim3(32, 8), 0, stream>>>(Wq, WqT, 1024, 512);
  cvt_transpose<<<dim3(16, 32), dim3(32, 8), 0, stream>>>(Wk, WkT, 1024, 512);
  cvt_transpose<<<dim3(32, 32), dim3(32, 8), 0, stream>>>(Wv, WvT, 1024, 1024);

  // 2) projections: Q = X WqT^T + bq, K = X WkT^T + bk  (bf16 out)
  gemm_nt<1, 1><<<dim3(4, 64, 1), 256, 0, stream>>>(Xb, 1024, 0, WqT, 1024, 0,
                                                    Qb, 512, 0, bq, 1.f, 1024);
  gemm_nt<1, 1><<<dim3(4, 64, 1), 256, 0, stream>>>(Xb, 1024, 0, WkT, 1024, 0,
                                                    Kb, 512, 0, bk, 1.f, 1024);
  // V^T[1024,8192] = WvT[1024,1024] * X^T  (+ bv per-row), bf16 out
  gemm_nt<1, 2><<<dim3(64, 8, 1), 256, 0, stream>>>(WvT, 1024, 0, Xb, 1024, 0,
                                                    VT, 8192, 0, bv, 1.f, 1024);

  // 3) scores[b] = Q[b] K[b]^T / sqrt(512)  (f32, batched)
  gemm_nt<0, 0><<<dim3(16, 16, 4), 256, 0, stream>>>(Qb, 512, 2048l * 512, Kb, 512, 2048l * 512,
                                                     SC, 2048, 2048l * 2048, nullptr,
                                                     0.044194173824159216f, 512);

  // 4) softmax rows -> P bf16 overlaid on SC (row stride 4096 bf16)
  softmax_rows<<<8192, 256, 0, stream>>>(SC);

  // 5) out[b] = P[b] V[b]   (P: lda 4096 bf16; Bt = V^T slice, ldb 8192, batch off 2048)
  gemm_nt<0, 0><<<dim3(8, 16, 4), 256, 0, stream>>>((const unsigned short*)SC, 4096, 2048l * 4096,
                                                    VT, 8192, 2048,
                                                    out, 1024, 2048l * 1024, nullptr, 1.f, 2048);
}

// Round 3
// 240.224 us; speedup vs baseline: 1.2497x; 1.2497x over previous
//
#include <hip/hip_runtime.h>
#include <hip/hip_bf16.h>

typedef __attribute__((ext_vector_type(8))) short short8;
typedef __attribute__((ext_vector_type(4))) float f32x4;
typedef __attribute__((ext_vector_type(4))) float float4v;
typedef __attribute__((ext_vector_type(8))) unsigned short ushort8;
typedef __attribute__((ext_vector_type(4))) unsigned short ushort4v;

__device__ __forceinline__ unsigned short f2bf(float f) {
  union { float f; unsigned u; } a; a.f = f;
  unsigned u = a.u;
  u += 0x7FFFu + ((u >> 16) & 1u);   // RTNE
  return (unsigned short)(u >> 16);
}

__device__ __forceinline__ void gload_lds16(const void* g, void* l) {
  __builtin_amdgcn_global_load_lds(
      (const __attribute__((address_space(1))) unsigned int*)g,
      (__attribute__((address_space(3))) unsigned int*)l, 16, 0, 0);
}

// ---------------- f32 -> bf16 convert (vectorized, grid-stride) ----------------
__global__ void cvt_bf16(const float* __restrict__ in, unsigned short* __restrict__ out, long n) {
  long i = ((long)blockIdx.x * blockDim.x + threadIdx.x) * 4;
  long stride = (long)gridDim.x * blockDim.x * 4;
  for (; i < n; i += stride) {
    float4v x = *(const float4v*)(in + i);
    ushort4v o;
    o.x = f2bf(x.x); o.y = f2bf(x.y); o.z = f2bf(x.z); o.w = f2bf(x.w);
    *(ushort4v*)(out + i) = o;
  }
}

// ------------- transpose + convert: W[R][C] f32 -> WT[C][R] bf16 ---------------
__global__ void cvt_transpose(const float* __restrict__ in, unsigned short* __restrict__ out,
                              int R, int C) {
  __shared__ float tile[32][33];
  int c0 = blockIdx.x * 32, r0 = blockIdx.y * 32;
#pragma unroll
  for (int i = 0; i < 4; ++i) {
    int r = r0 + threadIdx.y + i * 8;
    tile[threadIdx.y + i * 8][threadIdx.x] = in[(long)r * C + c0 + threadIdx.x];
  }
  __syncthreads();
#pragma unroll
  for (int i = 0; i < 4; ++i) {
    int rr = threadIdx.y + i * 8;
    int cc = threadIdx.x;
    out[(long)(c0 + rr) * R + r0 + cc] = f2bf(tile[cc][rr]);
  }
}

// ======================= deep-pipelined NT GEMM =======================
// C[M,N] = A[M,K] * Bt[N,K]^T, bf16 inputs, f32 accumulate.
// Tile: BM x 256, BK=64, 512 threads = 8 waves (2 M-waves x 4 N-waves).
// Per wave: (M_FR*16) x 64 output, acc = M_FR x 4 f32x4 fragments.
// LDS double-buffered; swizzle: slot(r,s) = r*8 + (s ^ (r&7))  (16B slots,
// 8 slots per 64-element bf16 row). Staging pre-swizzles the GLOBAL source
// so global_load_lds dest stays linear (wave-uniform base + lane*16).
// Pipeline: all of tile t+1's global_load_lds issued at iter-t start, drained
// (vmcnt(0)) at iter-t end -> ~full iter of MFMA covers the load latency.
// Raw s_barrier (NOT __syncthreads) so loads stay in flight across barriers.
template<int M_FR, int OUT_BF16, int BIAS_MODE>  // BIAS: 0 none, 1 per-col, 2 per-row
__global__ __launch_bounds__(512, 2)
void gemm8(const unsigned short* __restrict__ A, int lda, long strideA,
           const unsigned short* __restrict__ Bt, int ldb, long strideB,
           void* __restrict__ Cv, int ldc, long strideC,
           const float* __restrict__ bias, float scale, int K,
           int MT, int NTt) {
  constexpr int BM = M_FR * 32;
  constexpr int A_SLOTS = BM * 8;          // 16B slots per A K-tile
  constexpr int A_LOADS = A_SLOTS / 512;
  constexpr int B_LOADS = 4;               // 2048 slots / 512 threads
  constexpr int ABYTES = A_SLOTS * 16;
  constexpr int BBYTES = 32768;            // 256 rows * 128 B
  __shared__ char lds[2 * ABYTES + 2 * BBYTES];

  const int tid = threadIdx.x;
  const int nb = gridDim.x;                // % 8 == 0 for all our launches
  const int bid = blockIdx.x;
  const int wg = (bid & 7) * (nb >> 3) + (bid >> 3);   // XCD-bijective swizzle
  const int ntile = wg % NTt;
  const int mtile = (wg / NTt) % MT;
  const int bz = wg / (NTt * MT);

  const unsigned short* Ab = A + bz * strideA + (long)(mtile * BM) * lda;
  const unsigned short* Bb = Bt + bz * strideB + (long)(ntile * 256) * ldb;

  const int wave = tid >> 6, lane = tid & 63;
  const int wm = wave >> 2, wn = wave & 3;
  const int lr = lane & 15, u = lane >> 4;

  // staging source offsets (elements): linear LDS slot q holds global
  // (row = q>>3, kslot = (q&7) ^ (row&7))
  long aoffg[A_LOADS], boffg[B_LOADS];
#pragma unroll
  for (int i = 0; i < A_LOADS; ++i) {
    int q = i * 512 + tid, r = q >> 3, s = (q & 7) ^ (r & 7);
    aoffg[i] = (long)r * lda + s * 8;
  }
#pragma unroll
  for (int i = 0; i < B_LOADS; ++i) {
    int q = i * 512 + tid, r = q >> 3, s = (q & 7) ^ (r & 7);
    boffg[i] = (long)r * ldb + s * 8;
  }
  const int t16 = tid * 16;

  // fragment read bases (byte offsets within one buffer); row&7 == lr&7
  const int arow = (wm * (M_FR * 16) + lr) * 128;
  const int brow = (wn * 64 + lr) * 128;
  const int swz0 = (u ^ (lr & 7)) * 16;          // k-half 0: slot u
  const int swz1 = ((u + 4) ^ (lr & 7)) * 16;    // k-half 1: slot u+4

  f32x4 acc[M_FR][4];
#pragma unroll
  for (int m = 0; m < M_FR; ++m)
#pragma unroll
    for (int n = 0; n < 4; ++n) acc[m][n] = f32x4{0.f, 0.f, 0.f, 0.f};

  // prologue: stage tile 0 into buffer 0
  {
    char* la = lds;
    char* lb = lds + 2 * ABYTES;
#pragma unroll
    for (int i = 0; i < A_LOADS; ++i) gload_lds16(Ab + aoffg[i], la + i * 8192 + t16);
#pragma unroll
    for (int i = 0; i < B_LOADS; ++i) gload_lds16(Bb + boffg[i], lb + i * 8192 + t16);
  }
  asm volatile("s_waitcnt vmcnt(0)" ::: "memory");
  __builtin_amdgcn_s_barrier();
  __builtin_amdgcn_sched_barrier(0);

  const int NT = K >> 6;
  int cur = 0;
  for (int t = 0; t < NT; ++t) {
    {  // issue ALL of next tile's loads now; drained at iter end (~1 iter cover)
      const int knext = (t + 1 < NT) ? ((t + 1) << 6) : 0;  // wrap: harmless reload
      const unsigned short* An = Ab + knext;
      const unsigned short* Bn = Bb + knext;
      char* la = lds + (cur ^ 1) * ABYTES;
      char* lb = lds + 2 * ABYTES + (cur ^ 1) * BBYTES;
#pragma unroll
      for (int i = 0; i < A_LOADS; ++i) gload_lds16(An + aoffg[i], la + i * 8192 + t16);
#pragma unroll
      for (int i = 0; i < B_LOADS; ++i) gload_lds16(Bn + boffg[i], lb + i * 8192 + t16);
    }
    const char* la = lds + cur * ABYTES;
    const char* lb = lds + 2 * ABYTES + cur * BBYTES;
#pragma unroll
    for (int kh = 0; kh < 2; ++kh) {
      const int sw = kh ? swz1 : swz0;
      short8 bfr[4];
#pragma unroll
      for (int nf = 0; nf < 4; ++nf)
        bfr[nf] = *(const short8*)(lb + brow + nf * 2048 + sw);
#pragma unroll
      for (int ch = 0; ch < M_FR / 4; ++ch) {
        short8 afr[4];
#pragma unroll
        for (int i = 0; i < 4; ++i)
          afr[i] = *(const short8*)(la + arow + (ch * 4 + i) * 2048 + sw);
        __builtin_amdgcn_s_setprio(1);
#pragma unroll
        for (int i = 0; i < 4; ++i)
#pragma unroll
          for (int nf = 0; nf < 4; ++nf)
            acc[ch * 4 + i][nf] = __builtin_amdgcn_mfma_f32_16x16x32_bf16(
                afr[i], bfr[nf], acc[ch * 4 + i][nf], 0, 0, 0);
        __builtin_amdgcn_s_setprio(0);
        __builtin_amdgcn_sched_barrier(0);
        __builtin_amdgcn_s_barrier();
        __builtin_amdgcn_sched_barrier(0);
      }
    }
    // boundary: next tile's loads (issued at THIS iter's start) must be landed
    asm volatile("s_waitcnt vmcnt(0)" ::: "memory");
    __builtin_amdgcn_s_barrier();
    __builtin_amdgcn_sched_barrier(0);
    cur ^= 1;
  }

  // epilogue: C/D layout col = lane&15, row = (lane>>4)*4 + j
  const long cb = (long)bz * strideC;
  const int row0 = mtile * BM + wm * (M_FR * 16);
  const int col0 = ntile * 256 + wn * 64;
#pragma unroll
  for (int mf = 0; mf < M_FR; ++mf) {
#pragma unroll
    for (int nf = 0; nf < 4; ++nf) {
      const int col = col0 + nf * 16 + lr;
      float bc = (BIAS_MODE == 1) ? bias[col] : 0.f;
#pragma unroll
      for (int j = 0; j < 4; ++j) {
        const int row = row0 + mf * 16 + u * 4 + j;
        float val = acc[mf][nf][j] * scale + bc;
        if (BIAS_MODE == 2) val += bias[row];
        if (OUT_BF16)
          ((unsigned short*)Cv)[cb + (long)row * ldc + col] = f2bf(val);
        else
          ((float*)Cv)[cb + (long)row * ldc + col] = val;
      }
    }
  }
}

// --------- row softmax: scores f32 [8192][2048] -> P bf16 in-place (lda 4096) ---------
__global__ __launch_bounds__(256)
void softmax_rows(float* __restrict__ sc) {
  long row = blockIdx.x;
  float* p = sc + row * 2048;
  int tid = threadIdx.x;
  int wave = tid >> 6;

  float v[8];
  float4v x0 = *(const float4v*)(p + tid * 8);
  float4v x1 = *(const float4v*)(p + tid * 8 + 4);
  v[0] = x0.x; v[1] = x0.y; v[2] = x0.z; v[3] = x0.w;
  v[4] = x1.x; v[5] = x1.y; v[6] = x1.z; v[7] = x1.w;

  float m = -1e30f;
#pragma unroll
  for (int j = 0; j < 8; ++j) m = fmaxf(m, v[j]);
#pragma unroll
  for (int o = 32; o; o >>= 1) m = fmaxf(m, __shfl_xor(m, o));
  __shared__ float redm[4], reds[4];
  if ((tid & 63) == 0) redm[wave] = m;
  __syncthreads();
  m = fmaxf(fmaxf(redm[0], redm[1]), fmaxf(redm[2], redm[3]));

  float s = 0.f;
#pragma unroll
  for (int j = 0; j < 8; ++j) { v[j] = __expf(v[j] - m); s += v[j]; }
#pragma unroll
  for (int o = 32; o; o >>= 1) s += __shfl_xor(s, o);
  if ((tid & 63) == 0) reds[wave] = s;
  __syncthreads();
  s = reds[0] + reds[1] + reds[2] + reds[3];
  float inv = 1.0f / s;

  ushort8 o8;
#pragma unroll
  for (int j = 0; j < 8; ++j) o8[j] = f2bf(v[j] * inv);
  *(ushort8*)((unsigned short*)p + tid * 8) = o8;
}

// ------------------------------------------------------------------------------
extern "C" void kernel_launch(void* const* d_in, const int* in_sizes, int n_in,
                              void* d_out, int out_size, void* d_ws, size_t ws_size,
                              hipStream_t stream) {
  const float* X  = (const float*)d_in[0];
  const float* Wq = (const float*)d_in[1];
  const float* bq = (const float*)d_in[2];
  const float* Wk = (const float*)d_in[3];
  const float* bk = (const float*)d_in[4];
  const float* Wv = (const float*)d_in[5];
  const float* bv = (const float*)d_in[6];
  float* out = (float*)d_out;

  char* ws = (char*)d_ws;
  unsigned short* Xb  = (unsigned short*)(ws);                       // 16 MiB [8192,1024]
  unsigned short* WqT = (unsigned short*)(ws + (16l << 20));         //  1 MiB [512,1024]
  unsigned short* WkT = (unsigned short*)(ws + (17l << 20));         //  1 MiB
  unsigned short* WvT = (unsigned short*)(ws + (18l << 20));         //  2 MiB [1024,1024]
  unsigned short* Qb  = (unsigned short*)(ws + (20l << 20));         //  8 MiB [8192,512]
  unsigned short* Kb  = (unsigned short*)(ws + (28l << 20));         //  8 MiB
  unsigned short* VT  = (unsigned short*)(ws + (36l << 20));         // 16 MiB [1024,8192]
  float*          SC  = (float*)         (ws + (52l << 20));         // 64 MiB [4][2048][2048]

  // 1) conversions
  cvt_bf16<<<4096, 256, 0, stream>>>(X, Xb, 8388608);
  cvt_transpose<<<dim3(16, 32), dim3(32, 8), 0, stream>>>(Wq, WqT, 1024, 512);
  cvt_transpose<<<dim3(16, 32), dim3(32, 8), 0, stream>>>(Wk, WkT, 1024, 512);
  cvt_transpose<<<dim3(32, 32), dim3(32, 8), 0, stream>>>(Wv, WvT, 1024, 1024);

  // 2) projections (128x256 tiles): Q = X WqT^T + bq, K = X WkT^T + bk (bf16 out)
  gemm8<4, 1, 1><<<128, 512, 0, stream>>>(Xb, 1024, 0, WqT, 1024, 0,
                                          Qb, 512, 0, bq, 1.f, 1024, 64, 2);
  gemm8<4, 1, 1><<<128, 512, 0, stream>>>(Xb, 1024, 0, WkT, 1024, 0,
                                          Kb, 512, 0, bk, 1.f, 1024, 64, 2);
  // V^T[1024,8192] = WvT * X^T (+ bv per-row), bf16 out
  gemm8<4, 1, 2><<<256, 512, 0, stream>>>(WvT, 1024, 0, Xb, 1024, 0,
                                          VT, 8192, 0, bv, 1.f, 1024, 8, 32);

  // 3) scores[b] = Q[b] K[b]^T / sqrt(512)  (256x256 tiles, f32 out, batched)
  gemm8<8, 0, 0><<<256, 512, 0, stream>>>(Qb, 512, 2048l * 512, Kb, 512, 2048l * 512,
                                          SC, 2048, 2048l * 2048, nullptr,
                                          0.044194173824159216f, 512, 8, 8);

  // 4) softmax rows -> P bf16 overlaid on SC (row stride 4096 bf16)
  softmax_rows<<<8192, 256, 0, stream>>>(SC);

  // 5) out[b] = P[b] V[b]  (128x256 tiles; A = P lda 4096, Bt = V^T slice)
  gemm8<4, 0, 0><<<256, 512, 0, stream>>>((const unsigned short*)SC, 4096, 2048l * 4096,
                                          VT, 8192, 2048,
                                          out, 1024, 2048l * 1024, nullptr, 1.f, 2048, 16, 4);
}

// Round 4
// 220.793 us; speedup vs baseline: 1.3597x; 1.0880x over previous
//
#include <hip/hip_runtime.h>
#include <hip/hip_bf16.h>

typedef __attribute__((ext_vector_type(8))) short short8;
typedef __attribute__((ext_vector_type(4))) float f32x4;
typedef __attribute__((ext_vector_type(4))) float float4v;
typedef __attribute__((ext_vector_type(8))) unsigned short ushort8;
typedef __attribute__((ext_vector_type(4))) unsigned short ushort4v;

__device__ __forceinline__ unsigned short f2bf(float f) {
  union { float f; unsigned u; } a; a.f = f;
  unsigned u = a.u;
  u += 0x7FFFu + ((u >> 16) & 1u);   // RTNE
  return (unsigned short)(u >> 16);
}
__device__ __forceinline__ float bf2f(unsigned short h) {
  union { unsigned u; float f; } a; a.u = ((unsigned)h) << 16; return a.f;
}

__device__ __forceinline__ void gload_lds16(const void* g, void* l) {
  __builtin_amdgcn_global_load_lds(
      (const __attribute__((address_space(1))) unsigned int*)g,
      (__attribute__((address_space(3))) unsigned int*)l, 16, 0, 0);
}

// ---------------- f32 -> bf16 convert (vectorized, grid-stride) ----------------
__global__ void cvt_bf16(const float* __restrict__ in, unsigned short* __restrict__ out, long n) {
  long i = ((long)blockIdx.x * blockDim.x + threadIdx.x) * 4;
  long stride = (long)gridDim.x * blockDim.x * 4;
  for (; i < n; i += stride) {
    float4v x = *(const float4v*)(in + i);
    ushort4v o;
    o.x = f2bf(x.x); o.y = f2bf(x.y); o.z = f2bf(x.z); o.w = f2bf(x.w);
    *(ushort4v*)(out + i) = o;
  }
}

// ------------- transpose + convert: W[R][C] f32 -> WT[C][R] bf16 ---------------
__global__ void cvt_transpose(const float* __restrict__ in, unsigned short* __restrict__ out,
                              int R, int C) {
  __shared__ float tile[32][33];
  int c0 = blockIdx.x * 32, r0 = blockIdx.y * 32;
#pragma unroll
  for (int i = 0; i < 4; ++i) {
    int r = r0 + threadIdx.y + i * 8;
    tile[threadIdx.y + i * 8][threadIdx.x] = in[(long)r * C + c0 + threadIdx.x];
  }
  __syncthreads();
#pragma unroll
  for (int i = 0; i < 4; ++i) {
    int rr = threadIdx.y + i * 8;
    int cc = threadIdx.x;
    out[(long)(c0 + rr) * R + r0 + cc] = f2bf(tile[cc][rr]);
  }
}

__global__ void concat_bias(const float* __restrict__ a, const float* __restrict__ b,
                            float* __restrict__ o) {
  int i = blockIdx.x * 256 + threadIdx.x;   // 1024 total
  o[i] = (i < 512) ? a[i] : b[i - 512];
}

// ================= triple-buffered counted-vmcnt NT GEMM =================
// C[M,N] = A[M,K] * Bt[N,K]^T, bf16 in, f32 acc. BM=128, BN=256, BK=64,
// 512 thr = 8 waves (2M x 4N), per-wave 64x64 out (acc[4][4] f32x4).
// LDS: 3 buffers x (A 16KB + B 32KB) = 144 KB. Swizzle slot(r,s)=r*8+(s^(r&7));
// staging pre-swizzles the GLOBAL source so global_load_lds dest is linear.
// Pipeline: tile t -> buf t%3; iter t prefetches tile t+2 (3 loads per phase);
// gate = s_waitcnt vmcnt(6) (tile t+1's 6 loads STAY IN FLIGHT across the
// barrier -> ~1 full iter of latency cover; T4 counted-vmcnt, never 0 mid-loop).
template<int OUT_BF16, int BIAS_MODE>  // BIAS: 0 none, 1 per-col, 2 per-row
__global__ __launch_bounds__(512)
void gemm9(const unsigned short* __restrict__ A, int lda, long strideA,
           const unsigned short* __restrict__ Bt, int ldb, long strideB,
           void* __restrict__ Cv, int ldc, long strideC,
           const float* __restrict__ bias, float scale, int K,
           int MT, int NTt) {
  constexpr int ABYTES = 16384, BUFB = 49152;
  __shared__ char lds[3 * BUFB];

  const int tid = threadIdx.x;
  const int nb = gridDim.x, bid = blockIdx.x;       // nb % 8 == 0 always
  const int wg = (bid & 7) * (nb >> 3) + (bid >> 3);  // XCD-bijective swizzle
  const int ntile = wg % NTt;
  const int mtile = (wg / NTt) % MT;
  const int bz = wg / (NTt * MT);

  const unsigned short* Ab = A + bz * strideA + (long)(mtile * 128) * lda;
  const unsigned short* Bb = Bt + bz * strideB + (long)(ntile * 256) * ldb;

  const int wave = tid >> 6, lane = tid & 63;
  const int wm = wave >> 2, wn = wave & 3;
  const int lr = lane & 15, u = lane >> 4;

  // staging global offsets (elements): linear LDS slot q holds global
  // (row = q>>3, kslot = (q&7)^(row&7))
  long aoffg[2], boffg[4];
#pragma unroll
  for (int i = 0; i < 2; ++i) {
    int q = i * 512 + tid, r = q >> 3, s = (q & 7) ^ (r & 7);
    aoffg[i] = (long)r * lda + s * 8;
  }
#pragma unroll
  for (int i = 0; i < 4; ++i) {
    int q = i * 512 + tid, r = q >> 3, s = (q & 7) ^ (r & 7);
    boffg[i] = (long)r * ldb + s * 8;
  }
  const int t16 = tid * 16;

  // fragment read bases (bytes within one buffer)
  const int arow = (wm * 64 + lr) * 128;
  const int brow = (wn * 64 + lr) * 128;
  const int swz0 = (u ^ (lr & 7)) * 16;          // kh=0: k-unit u
  const int swz1 = ((u + 4) ^ (lr & 7)) * 16;    // kh=1: k-unit u+4

  f32x4 acc[4][4];
#pragma unroll
  for (int m = 0; m < 4; ++m)
#pragma unroll
    for (int n = 0; n < 4; ++n) acc[m][n] = f32x4{0.f, 0.f, 0.f, 0.f};

  const int NT = K >> 6;

  // prologue: stage tile 0 -> buf0, tile 1 -> buf1 (12 loads in flight, FIFO)
#pragma unroll
  for (int tt = 0; tt < 2; ++tt) {
    char* la = lds + tt * BUFB;
    char* lb = la + ABYTES;
    const unsigned short* As = Ab + (tt << 6);
    const unsigned short* Bs = Bb + (tt << 6);
    gload_lds16(As + aoffg[0], la + t16);
    gload_lds16(As + aoffg[1], la + 8192 + t16);
    gload_lds16(Bs + boffg[0], lb + t16);
    gload_lds16(Bs + boffg[1], lb + 8192 + t16);
    gload_lds16(Bs + boffg[2], lb + 16384 + t16);
    gload_lds16(Bs + boffg[3], lb + 24576 + t16);
  }

  int cb_ = 0, nb_ = 2;   // buf index of tile t and tile t+2 (mod-3 counters)
  for (int t = 0; t < NT; ++t) {
    const char* la = lds + cb_ * BUFB;
    const char* lb = la + ABYTES;
    char* pa = lds + nb_ * BUFB;
    char* pb = pa + ABYTES;
    const bool pf = (t + 2) < NT;
    const unsigned short* An = Ab + ((t + 2) << 6);
    const unsigned short* Bn = Bb + ((t + 2) << 6);

    // gate: tile t must be landed; tile t+1's 6 loads may remain in flight
    if (t + 1 < NT) asm volatile("s_waitcnt vmcnt(6)" ::: "memory");
    else            asm volatile("s_waitcnt vmcnt(0)" ::: "memory");
    __builtin_amdgcn_s_barrier();
    __builtin_amdgcn_sched_barrier(0);

    // ---- phase 0 (kh=0) ----
    if (pf) {   // chunk0 of tile t+2: A0, A1, B0
      gload_lds16(An + aoffg[0], pa + t16);
      gload_lds16(An + aoffg[1], pa + 8192 + t16);
      gload_lds16(Bn + boffg[0], pb + t16);
    }
    {
      short8 afr[4], bfr[4];
#pragma unroll
      for (int nf = 0; nf < 4; ++nf) bfr[nf] = *(const short8*)(lb + brow + nf * 2048 + swz0);
#pragma unroll
      for (int mf = 0; mf < 4; ++mf) afr[mf] = *(const short8*)(la + arow + mf * 2048 + swz0);
      __builtin_amdgcn_s_setprio(1);
#pragma unroll
      for (int mf = 0; mf < 4; ++mf)
#pragma unroll
        for (int nf = 0; nf < 4; ++nf)
          acc[mf][nf] = __builtin_amdgcn_mfma_f32_16x16x32_bf16(afr[mf], bfr[nf], acc[mf][nf], 0, 0, 0);
      __builtin_amdgcn_s_setprio(0);
    }
    __builtin_amdgcn_sched_barrier(0);
    __builtin_amdgcn_s_barrier();
    __builtin_amdgcn_sched_barrier(0);

    // ---- phase 1 (kh=1) ----
    if (pf) {   // chunk1 of tile t+2: B1, B2, B3
      gload_lds16(Bn + boffg[1], pb + 8192 + t16);
      gload_lds16(Bn + boffg[2], pb + 16384 + t16);
      gload_lds16(Bn + boffg[3], pb + 24576 + t16);
    }
    {
      short8 afr[4], bfr[4];
#pragma unroll
      for (int nf = 0; nf < 4; ++nf) bfr[nf] = *(const short8*)(lb + brow + nf * 2048 + swz1);
#pragma unroll
      for (int mf = 0; mf < 4; ++mf) afr[mf] = *(const short8*)(la + arow + mf * 2048 + swz1);
      __builtin_amdgcn_s_setprio(1);
#pragma unroll
      for (int mf = 0; mf < 4; ++mf)
#pragma unroll
        for (int nf = 0; nf < 4; ++nf)
          acc[mf][nf] = __builtin_amdgcn_mfma_f32_16x16x32_bf16(afr[mf], bfr[nf], acc[mf][nf], 0, 0, 0);
      __builtin_amdgcn_s_setprio(0);
    }
    __builtin_amdgcn_sched_barrier(0);

    cb_ = (cb_ == 2) ? 0 : cb_ + 1;
    nb_ = (nb_ == 2) ? 0 : nb_ + 1;
  }

  // epilogue: C/D layout col = lane&15, row = (lane>>4)*4 + j
  const long cbase = (long)bz * strideC;
  const int row0 = mtile * 128 + wm * 64;
  const int col0 = ntile * 256 + wn * 64;
#pragma unroll
  for (int mf = 0; mf < 4; ++mf) {
#pragma unroll
    for (int nf = 0; nf < 4; ++nf) {
      const int col = col0 + nf * 16 + lr;
      float bc = (BIAS_MODE == 1) ? bias[col] : 0.f;
#pragma unroll
      for (int j = 0; j < 4; ++j) {
        const int row = row0 + mf * 16 + u * 4 + j;
        float val = acc[mf][nf][j] * scale + bc;
        if (BIAS_MODE == 2) val += bias[row];
        if (OUT_BF16)
          ((unsigned short*)Cv)[cbase + (long)row * ldc + col] = f2bf(val);
        else
          ((float*)Cv)[cbase + (long)row * ldc + col] = val;
      }
    }
  }
}

// ------- row softmax over bf16 scores, in place: [8192][2048] bf16 -------
__global__ __launch_bounds__(256)
void softmax_rows_bf16(unsigned short* __restrict__ sc) {
  long row = blockIdx.x;
  unsigned short* p = sc + row * 2048;
  int tid = threadIdx.x;
  int wave = tid >> 6;

  ushort8 x = *(const ushort8*)(p + tid * 8);
  float v[8];
#pragma unroll
  for (int j = 0; j < 8; ++j) v[j] = bf2f(x[j]);

  float m = -1e30f;
#pragma unroll
  for (int j = 0; j < 8; ++j) m = fmaxf(m, v[j]);
#pragma unroll
  for (int o = 32; o; o >>= 1) m = fmaxf(m, __shfl_xor(m, o));
  __shared__ float redm[4], reds[4];
  if ((tid & 63) == 0) redm[wave] = m;
  __syncthreads();
  m = fmaxf(fmaxf(redm[0], redm[1]), fmaxf(redm[2], redm[3]));

  float s = 0.f;
#pragma unroll
  for (int j = 0; j < 8; ++j) { v[j] = __expf(v[j] - m); s += v[j]; }
#pragma unroll
  for (int o = 32; o; o >>= 1) s += __shfl_xor(s, o);
  if ((tid & 63) == 0) reds[wave] = s;
  __syncthreads();
  s = reds[0] + reds[1] + reds[2] + reds[3];
  float inv = 1.0f / s;

  ushort8 o8;
#pragma unroll
  for (int j = 0; j < 8; ++j) o8[j] = f2bf(v[j] * inv);
  *(ushort8*)(p + tid * 8) = o8;
}

// ------------------------------------------------------------------------------
extern "C" void kernel_launch(void* const* d_in, const int* in_sizes, int n_in,
                              void* d_out, int out_size, void* d_ws, size_t ws_size,
                              hipStream_t stream) {
  const float* X  = (const float*)d_in[0];
  const float* Wq = (const float*)d_in[1];
  const float* bq = (const float*)d_in[2];
  const float* Wk = (const float*)d_in[3];
  const float* bk = (const float*)d_in[4];
  const float* Wv = (const float*)d_in[5];
  const float* bv = (const float*)d_in[6];
  float* out = (float*)d_out;

  char* ws = (char*)d_ws;
  unsigned short* Xb   = (unsigned short*)(ws);                 // 16 MiB [8192,1024]
  unsigned short* WqkT = (unsigned short*)(ws + (16l << 20));   //  2 MiB [1024,1024] (rows 0-511 Wq^T, 512-1023 Wk^T)
  unsigned short* WvT  = (unsigned short*)(ws + (18l << 20));   //  2 MiB [1024,1024]
  float*          bqk  = (float*)         (ws + (20l << 20));   //  4 KiB [1024]
  unsigned short* QKb  = (unsigned short*)(ws + (21l << 20));   // 16 MiB [8192,1024] (cols 0-511 Q, 512-1023 K)
  unsigned short* VT   = (unsigned short*)(ws + (37l << 20));   // 16 MiB [1024,8192]
  unsigned short* SC   = (unsigned short*)(ws + (53l << 20));   // 32 MiB [4][2048][2048] bf16

  // 1) conversions / layout prep
  cvt_bf16<<<4096, 256, 0, stream>>>(X, Xb, 8388608);
  cvt_transpose<<<dim3(16, 32), dim3(32, 8), 0, stream>>>(Wq, WqkT, 1024, 512);
  cvt_transpose<<<dim3(16, 32), dim3(32, 8), 0, stream>>>(Wk, WqkT + 512 * 1024, 1024, 512);
  cvt_transpose<<<dim3(32, 32), dim3(32, 8), 0, stream>>>(Wv, WvT, 1024, 1024);
  concat_bias<<<4, 256, 0, stream>>>(bq, bk, bqk);

  // 2) fused Q|K projection: QKb = Xb * WqkT^T + [bq;bk]  (bf16 out)
  gemm9<1, 1><<<256, 512, 0, stream>>>(Xb, 1024, 0, WqkT, 1024, 0,
                                       QKb, 1024, 0, bqk, 1.f, 1024, 64, 4);
  // V^T[1024,8192] = WvT * Xb^T (+ bv per-row), bf16 out
  gemm9<1, 2><<<256, 512, 0, stream>>>(WvT, 1024, 0, Xb, 1024, 0,
                                       VT, 8192, 0, bv, 1.f, 1024, 8, 32);

  // 3) scores[b] = Q[b] K[b]^T / sqrt(512)  (bf16 out, batched)
  gemm9<1, 0><<<512, 512, 0, stream>>>(QKb, 1024, 2048l * 1024, QKb + 512, 1024, 2048l * 1024,
                                       SC, 2048, 2048l * 2048, nullptr,
                                       0.044194173824159216f, 512, 16, 8);

  // 4) softmax rows, bf16 in-place
  softmax_rows_bf16<<<8192, 256, 0, stream>>>(SC);

  // 5) out[b] = P[b] V[b]  (A = P bf16 lda 2048; Bt = V^T batch slice)
  gemm9<0, 0><<<256, 512, 0, stream>>>(SC, 2048, 2048l * 2048, VT, 8192, 2048,
                                       out, 1024, 2048l * 1024, nullptr, 1.f, 2048, 16, 4);
}

// Round 7
// 215.716 us; speedup vs baseline: 1.3917x; 1.0235x over previous
//
#include <hip/hip_runtime.h>
#include <hip/hip_bf16.h>

typedef __attribute__((ext_vector_type(8))) short short8;
typedef __attribute__((ext_vector_type(4))) float f32x4;
typedef __attribute__((ext_vector_type(4))) float float4v;
typedef __attribute__((ext_vector_type(8))) unsigned short ushort8;
typedef __attribute__((ext_vector_type(4))) unsigned short ushort4v;

__device__ __forceinline__ unsigned short f2bf(float f) {
  union { float f; unsigned u; } a; a.f = f;
  unsigned u = a.u;
  u += 0x7FFFu + ((u >> 16) & 1u);   // RTNE
  return (unsigned short)(u >> 16);
}
__device__ __forceinline__ float bf2f(unsigned short h) {
  union { unsigned u; float f; } a; a.u = ((unsigned)h) << 16; return a.f;
}

__device__ __forceinline__ void gload_lds16(const void* g, void* l) {
  __builtin_amdgcn_global_load_lds(
      (const __attribute__((address_space(1))) unsigned int*)g,
      (__attribute__((address_space(3))) unsigned int*)l, 16, 0, 0);
}

// ---------------- f32 -> bf16 convert (vectorized, grid-stride) ----------------
__global__ void cvt_bf16(const float* __restrict__ in, unsigned short* __restrict__ out, long n) {
  long i = ((long)blockIdx.x * blockDim.x + threadIdx.x) * 4;
  long stride = (long)gridDim.x * blockDim.x * 4;
  for (; i < n; i += stride) {
    float4v x = *(const float4v*)(in + i);
    ushort4v o;
    o.x = f2bf(x.x); o.y = f2bf(x.y); o.z = f2bf(x.z); o.w = f2bf(x.w);
    *(ushort4v*)(out + i) = o;
  }
}

// ------------- transpose + convert: W[R][C] f32 -> WT[C][R] bf16 ---------------
__global__ void cvt_transpose(const float* __restrict__ in, unsigned short* __restrict__ out,
                              int R, int C) {
  __shared__ float tile[32][33];
  int c0 = blockIdx.x * 32, r0 = blockIdx.y * 32;
#pragma unroll
  for (int i = 0; i < 4; ++i) {
    int r = r0 + threadIdx.y + i * 8;
    tile[threadIdx.y + i * 8][threadIdx.x] = in[(long)r * C + c0 + threadIdx.x];
  }
  __syncthreads();
#pragma unroll
  for (int i = 0; i < 4; ++i) {
    int rr = threadIdx.y + i * 8;
    int cc = threadIdx.x;
    out[(long)(c0 + rr) * R + r0 + cc] = f2bf(tile[cc][rr]);
  }
}

__global__ void concat_bias(const float* __restrict__ a, const float* __restrict__ b,
                            float* __restrict__ o) {
  int i = blockIdx.x * 256 + threadIdx.x;   // 1024 total
  o[i] = (i < 512) ? a[i] : b[i - 512];
}

// ============ minimal-sync mod-3-buffered NT GEMM (256x128, BK=64) ============
// C[M,N] = A[M,K] * Bt[N,K]^T, bf16 in, f32 acc. 512 thr = 8 waves (4M x 2N),
// per-wave 64x64 out = acc[4][4] f32x4. LDS: 3 whole-tile buffers x 48KB
// (A 32KB + B 16KB) = 144KB -> tile t lives in buf t%3; iter t prefetches
// tile t+2. Writes NEVER alias a live buffer (mod-3), so only ONE barrier per
// iter is needed: gate {vmcnt(6), s_barrier}. ds_reads issue right after the
// gate with NO intra-body sched-barrier pinning -> compiler overlaps
// reads/gloads/MFMA and waves drift within the iter. A single sched_barrier(0)
// at the END of the iter pins all iter-t work (incl. MFMAs + their lgkm waits)
// before the gate, guaranteeing tile-t reads completed before any wave passes
// barrier t+1 (whose prefetch overwrites buf t%3 via loads landing >=200cy later).
// Swizzle slot(r,s)=r*8+(s^(r&7)) (16B slots); staging pre-swizzles the GLOBAL
// source so global_load_lds dest stays linear.
template<int OUT_BF16, int BIAS_MODE>  // BIAS: 0 none, 1 per-col, 2 per-row
__global__ __launch_bounds__(512)
void gemmA(const unsigned short* __restrict__ A, int lda, long strideA,
           const unsigned short* __restrict__ Bt, int ldb, long strideB,
           void* __restrict__ Cv, int ldc, long strideC,
           const float* __restrict__ bias, float scale, int K,
           int MT, int NTt) {
  constexpr int ABYTES = 32768;            // 256 rows * 128 B
  constexpr int BUFB = 49152;              // + B 128 rows * 128 B
  __shared__ char lds[3 * BUFB];           // 147456 B

  const int tid = threadIdx.x;
  const int nb = gridDim.x, bid = blockIdx.x;         // nb % 8 == 0 always
  const int wg = (bid & 7) * (nb >> 3) + (bid >> 3);  // XCD-bijective swizzle
  const int ntile = wg % NTt;
  const int mtile = (wg / NTt) % MT;
  const int bz = wg / (NTt * MT);

  const unsigned short* Ab = A + bz * strideA + (long)(mtile * 256) * lda;
  const unsigned short* Bb = Bt + bz * strideB + (long)(ntile * 128) * ldb;

  const int wave = tid >> 6, lane = tid & 63;
  const int wm = wave >> 1, wn = wave & 1;
  const int lr = lane & 15, u = lane >> 4;

  // staging global offsets (elements): linear LDS slot q holds global
  // (row = q>>3, kslot = (q&7)^(row&7))
  long aoffg[4], boffg[2];
#pragma unroll
  for (int i = 0; i < 4; ++i) {
    int q = i * 512 + tid, r = q >> 3, s = (q & 7) ^ (r & 7);
    aoffg[i] = (long)r * lda + s * 8;
  }
#pragma unroll
  for (int i = 0; i < 2; ++i) {
    int q = i * 512 + tid, r = q >> 3, s = (q & 7) ^ (r & 7);
    boffg[i] = (long)r * ldb + s * 8;
  }
  const int t16 = tid * 16;

  // fragment read bases (bytes within one buffer); row&7 == lr&7 everywhere
  const int arow = (wm * 64 + lr) * 128;            // A rows: wm*64 + mf*16 + lr
  const int brow = ABYTES + (wn * 64 + lr) * 128;   // B rows: wn*64 + nf*16 + lr
  const int swk0 = (u ^ (lr & 7)) * 16;             // k-units 0..3
  const int swk1 = ((u + 4) ^ (lr & 7)) * 16;       // k-units 4..7

  f32x4 acc[4][4];
#pragma unroll
  for (int m = 0; m < 4; ++m)
#pragma unroll
    for (int n = 0; n < 4; ++n) acc[m][n] = f32x4{0.f, 0.f, 0.f, 0.f};

  const int NT = K >> 6;

  // prologue: stage tile 0 -> buf0, tile 1 -> buf1 (12 loads in flight, FIFO)
#pragma unroll
  for (int tt = 0; tt < 2; ++tt) {
    char* lb = lds + tt * BUFB;
    const unsigned short* As = Ab + (tt << 6);
    const unsigned short* Bs = Bb + (tt << 6);
    gload_lds16(As + aoffg[0], lb + t16);
    gload_lds16(As + aoffg[1], lb + 8192 + t16);
    gload_lds16(As + aoffg[2], lb + 16384 + t16);
    gload_lds16(As + aoffg[3], lb + 24576 + t16);
    gload_lds16(Bs + boffg[0], lb + ABYTES + t16);
    gload_lds16(Bs + boffg[1], lb + ABYTES + 8192 + t16);
  }

  int cb_ = 0, pb_ = 2;   // buf of tile t / tile t+2 (mod-3 counters)
  for (int t = 0; t < NT; ++t) {
    // gate: tile t landed; tile t+1's 6 loads stay in flight across the barrier
    if (t + 1 < NT) asm volatile("s_waitcnt vmcnt(6)" ::: "memory");
    else            asm volatile("s_waitcnt vmcnt(0)" ::: "memory");
    __builtin_amdgcn_s_barrier();

    const char* la = lds + cb_ * BUFB;

    // fragment loads (compiler schedules; fine-grained lgkmcnt before MFMA use)
    short8 af[2][4], bf[2][4];
#pragma unroll
    for (int mf = 0; mf < 4; ++mf) {
      af[0][mf] = *(const short8*)(la + arow + mf * 2048 + swk0);
      af[1][mf] = *(const short8*)(la + arow + mf * 2048 + swk1);
    }
#pragma unroll
    for (int nf = 0; nf < 4; ++nf) {
      bf[0][nf] = *(const short8*)(la + brow + nf * 2048 + swk0);
      bf[1][nf] = *(const short8*)(la + brow + nf * 2048 + swk1);
    }

    // prefetch tile t+2 -> buf pb_ (safe: mod-3, and all waves passed the gate)
    if (t + 2 < NT) {
      char* lp = lds + pb_ * BUFB;
      const unsigned short* An = Ab + ((t + 2) << 6);
      const unsigned short* Bn = Bb + ((t + 2) << 6);
      gload_lds16(An + aoffg[0], lp + t16);
      gload_lds16(An + aoffg[1], lp + 8192 + t16);
      gload_lds16(An + aoffg[2], lp + 16384 + t16);
      gload_lds16(An + aoffg[3], lp + 24576 + t16);
      gload_lds16(Bn + boffg[0], lp + ABYTES + t16);
      gload_lds16(Bn + boffg[1], lp + ABYTES + 8192 + t16);
    }

    __builtin_amdgcn_s_setprio(1);
#pragma unroll
    for (int kh = 0; kh < 2; ++kh)
#pragma unroll
      for (int mf = 0; mf < 4; ++mf)
#pragma unroll
        for (int nf = 0; nf < 4; ++nf)
          acc[mf][nf] = __builtin_amdgcn_mfma_f32_16x16x32_bf16(
              af[kh][mf], bf[kh][nf], acc[mf][nf], 0, 0, 0);
    __builtin_amdgcn_s_setprio(0);
    // pin iter-t work before the next gate (prevents back-edge sinking; does
    // NOT constrain scheduling within the iter body above)
    __builtin_amdgcn_sched_barrier(0);

    cb_ = (cb_ == 2) ? 0 : cb_ + 1;
    pb_ = (pb_ == 2) ? 0 : pb_ + 1;
  }

  // epilogue: C/D layout col = lane&15, row = (lane>>4)*4 + j
  const long cbase = (long)bz * strideC;
  const int row0 = mtile * 256 + wm * 64;
  const int col0 = ntile * 128 + wn * 64;
#pragma unroll
  for (int mf = 0; mf < 4; ++mf) {
#pragma unroll
    for (int nf = 0; nf < 4; ++nf) {
      const int col = col0 + nf * 16 + lr;
      float bc = (BIAS_MODE == 1) ? bias[col] : 0.f;
#pragma unroll
      for (int j = 0; j < 4; ++j) {
        const int row = row0 + mf * 16 + u * 4 + j;
        float val = acc[mf][nf][j] * scale + bc;
        if (BIAS_MODE == 2) val += bias[row];
        if (OUT_BF16)
          ((unsigned short*)Cv)[cbase + (long)row * ldc + col] = f2bf(val);
        else
          ((float*)Cv)[cbase + (long)row * ldc + col] = val;
      }
    }
  }
}

// ------- row softmax over bf16 scores, in place: [8192][2048] bf16 -------
__global__ __launch_bounds__(256)
void softmax_rows_bf16(unsigned short* __restrict__ sc) {
  long row = blockIdx.x;
  unsigned short* p = sc + row * 2048;
  int tid = threadIdx.x;
  int wave = tid >> 6;

  ushort8 x = *(const ushort8*)(p + tid * 8);
  float v[8];
#pragma unroll
  for (int j = 0; j < 8; ++j) v[j] = bf2f(x[j]);

  float m = -1e30f;
#pragma unroll
  for (int j = 0; j < 8; ++j) m = fmaxf(m, v[j]);
#pragma unroll
  for (int o = 32; o; o >>= 1) m = fmaxf(m, __shfl_xor(m, o));
  __shared__ float redm[4], reds[4];
  if ((tid & 63) == 0) redm[wave] = m;
  __syncthreads();
  m = fmaxf(fmaxf(redm[0], redm[1]), fmaxf(redm[2], redm[3]));

  float s = 0.f;
#pragma unroll
  for (int j = 0; j < 8; ++j) { v[j] = __expf(v[j] - m); s += v[j]; }
#pragma unroll
  for (int o = 32; o; o >>= 1) s += __shfl_xor(s, o);
  if ((tid & 63) == 0) reds[wave] = s;
  __syncthreads();
  s = reds[0] + reds[1] + reds[2] + reds[3];
  float inv = 1.0f / s;

  ushort8 o8;
#pragma unroll
  for (int j = 0; j < 8; ++j) o8[j] = f2bf(v[j] * inv);
  *(ushort8*)(p + tid * 8) = o8;
}

// ------------------------------------------------------------------------------
extern "C" void kernel_launch(void* const* d_in, const int* in_sizes, int n_in,
                              void* d_out, int out_size, void* d_ws, size_t ws_size,
                              hipStream_t stream) {
  const float* X  = (const float*)d_in[0];
  const float* Wq = (const float*)d_in[1];
  const float* bq = (const float*)d_in[2];
  const float* Wk = (const float*)d_in[3];
  const float* bk = (const float*)d_in[4];
  const float* Wv = (const float*)d_in[5];
  const float* bv = (const float*)d_in[6];
  float* out = (float*)d_out;

  char* ws = (char*)d_ws;
  unsigned short* Xb   = (unsigned short*)(ws);                 // 16 MiB [8192,1024]
  unsigned short* WqkT = (unsigned short*)(ws + (16l << 20));   //  2 MiB [1024,1024] (rows 0-511 Wq^T, 512-1023 Wk^T)
  unsigned short* WvT  = (unsigned short*)(ws + (18l << 20));   //  2 MiB [1024,1024]
  float*          bqk  = (float*)         (ws + (20l << 20));   //  4 KiB [1024]
  unsigned short* QKb  = (unsigned short*)(ws + (21l << 20));   // 16 MiB [8192,1024] (cols 0-511 Q, 512-1023 K)
  unsigned short* VT   = (unsigned short*)(ws + (37l << 20));   // 16 MiB [1024,8192]
  unsigned short* SC   = (unsigned short*)(ws + (53l << 20));   // 32 MiB [4][2048][2048] bf16

  // 1) conversions / layout prep
  cvt_bf16<<<4096, 256, 0, stream>>>(X, Xb, 8388608);
  cvt_transpose<<<dim3(16, 32), dim3(32, 8), 0, stream>>>(Wq, WqkT, 1024, 512);
  cvt_transpose<<<dim3(16, 32), dim3(32, 8), 0, stream>>>(Wk, WqkT + 512 * 1024, 1024, 512);
  cvt_transpose<<<dim3(32, 32), dim3(32, 8), 0, stream>>>(Wv, WvT, 1024, 1024);
  concat_bias<<<4, 256, 0, stream>>>(bq, bk, bqk);

  // 2) fused Q|K projection: QKb = Xb * WqkT^T + [bq;bk]  (bf16 out)
  gemmA<1, 1><<<256, 512, 0, stream>>>(Xb, 1024, 0, WqkT, 1024, 0,
                                       QKb, 1024, 0, bqk, 1.f, 1024, 32, 8);
  // V^T[1024,8192] = WvT * Xb^T (+ bv per-row), bf16 out
  gemmA<1, 2><<<256, 512, 0, stream>>>(WvT, 1024, 0, Xb, 1024, 0,
                                       VT, 8192, 0, bv, 1.f, 1024, 4, 64);

  // 3) scores[b] = Q[b] K[b]^T / sqrt(512)  (bf16 out, batched)
  gemmA<1, 0><<<512, 512, 0, stream>>>(QKb, 1024, 2048l * 1024, QKb + 512, 1024, 2048l * 1024,
                                       SC, 2048, 2048l * 2048, nullptr,
                                       0.044194173824159216f, 512, 8, 16);

  // 4) softmax rows, bf16 in-place
  softmax_rows_bf16<<<8192, 256, 0, stream>>>(SC);

  // 5) out[b] = P[b] V[b]  (A = P bf16 lda 2048; Bt = V^T batch slice)
  gemmA<0, 0><<<256, 512, 0, stream>>>(SC, 2048, 2048l * 2048, VT, 8192, 2048,
                                       out, 1024, 2048l * 1024, nullptr, 1.f, 2048, 8, 8);
}